// Round 1
// baseline (366.464 us; speedup 1.0000x reference)
//
#include <hip/hip_runtime.h>
#include <hip/hip_bf16.h>
#include <stdint.h>

typedef unsigned short u16;
typedef short bf16x8 __attribute__((ext_vector_type(8)));
typedef u16   u16x8  __attribute__((ext_vector_type(8)));
typedef u16   u16x4  __attribute__((ext_vector_type(4)));
typedef float f32x4  __attribute__((ext_vector_type(4)));

__device__ inline u16 f2bf(float f) {
    uint32_t u = __builtin_bit_cast(uint32_t, f);
    uint32_t r = (u + 0x7FFFu + ((u >> 16) & 1u)) >> 16;
    return (u16)r;
}

__device__ inline void gload16(const void* g, void* l) {
    __builtin_amdgcn_global_load_lds((const __attribute__((address_space(1))) void*)g,
                                     (__attribute__((address_space(3))) void*)l, 16, 0, 0);
}

#define MFMA16(a, b, c) __builtin_amdgcn_mfma_f32_16x16x32_bf16((a), (b), (c), 0, 0, 0)

// ---------------- prep: gather even rows of x, cast to bf16 -----------------
// xe[t][k] = bf16(x[b][2*tt][k]), t = b*4096 + tt
__global__ __launch_bounds__(256) void k_prep_xe(const float* __restrict__ x,
                                                 u16* __restrict__ xe) {
    int row = blockIdx.x;              // 0..8191
    int b = row >> 12, tt = row & 4095;
    const float* src = x + ((size_t)b * 8192 + 2 * (size_t)tt) * 1024;
    float4 v = ((const float4*)src)[threadIdx.x];
    u16x4 o = { f2bf(v.x), f2bf(v.y), f2bf(v.z), f2bf(v.w) };
    *(u16x4*)(xe + (size_t)row * 1024 + threadIdx.x * 4) = o;
}

// ---------------- prep: transpose + cast weights to B^T layout --------------
// dst[layer*rowPer + e0+e][layer*colPer + k0+k] = bf16(src[layer*layerStride + (k0+k)*srcCols + e0+e])
__global__ __launch_bounds__(256) void k_transpose_cast(
    const float* __restrict__ src, u16* __restrict__ dst,
    int srcCols, size_t srcLayerStride, int dstStride, int dstRowPer, int dstColPer) {
    int k0 = blockIdx.x * 64, e0 = blockIdx.y * 64, layer = blockIdx.z;
    const float* s = src + (size_t)layer * srcLayerStride;
    __shared__ u16 T[64][66];
    int t = threadIdx.x;
#pragma unroll
    for (int p = 0; p < 16; ++p) {
        int l = p * 256 + t;
        int kl = l >> 6, el = l & 63;
        T[kl][el] = f2bf(s[(size_t)(k0 + kl) * srcCols + e0 + el]);
    }
    __syncthreads();
    int rowBase = layer * dstRowPer + e0;
    int colBase = layer * dstColPer + k0;
#pragma unroll
    for (int p = 0; p < 16; ++p) {
        int l = p * 256 + t;
        int eo = l >> 6, ko = l & 63;
        dst[(size_t)(rowBase + eo) * dstStride + colBase + ko] = T[ko][eo];
    }
}

// ---------------- GEMM: C[M,N] = A[M,K] @ BT[N,K]^T (+bias) -----------------
// 128x128 tile, BK=32, 4 waves (2x2), 16x16x32 bf16 MFMA, global_load_lds staging.
template <bool BF16OUT>
__global__ __launch_bounds__(256) void k_gemm_bt(
    const u16* __restrict__ A, const u16* __restrict__ B, void* __restrict__ C,
    const float* __restrict__ bias0, const float* __restrict__ bias1,
    const float* __restrict__ bias2, int K, int lda, int ldb, int ldc) {
    __shared__ __align__(16) char smem[16384];   // As 8KB | Bs 8KB
    const int tid = threadIdx.x;
    const int lane = tid & 63, wave = tid >> 6;
    const int wr = wave >> 1, wc = wave & 1;
    const int row0 = blockIdx.x * 128, col0 = blockIdx.y * 128;
    f32x4 acc[4][4] = {};
    const int nk = K >> 5;
    const char* Abase = (const char*)(A + (size_t)row0 * lda);
    const char* Bbase = (const char*)(B + (size_t)col0 * ldb);
    char* ldsA = smem;
    char* ldsB = smem + 8192;
    const size_t lda2 = (size_t)lda * 2, ldb2 = (size_t)ldb * 2;
    const int c0 = tid;          // chunk ids: row = c>>2, kbyte = (c&3)*16
    const int c1 = tid + 256;

    for (int ks = 0; ks < nk; ++ks) {
        const size_t kb0 = (size_t)(ks * 32) * 2;
        gload16(Abase + (size_t)(c0 >> 2) * lda2 + kb0 + (c0 & 3) * 16, ldsA + wave * 1024);
        gload16(Abase + (size_t)(c1 >> 2) * lda2 + kb0 + (c1 & 3) * 16, ldsA + 4096 + wave * 1024);
        gload16(Bbase + (size_t)(c0 >> 2) * ldb2 + kb0 + (c0 & 3) * 16, ldsB + wave * 1024);
        gload16(Bbase + (size_t)(c1 >> 2) * ldb2 + kb0 + (c1 & 3) * 16, ldsB + 4096 + wave * 1024);
        __syncthreads();
        bf16x8 af[4], bfr[4];
        const int kb = (lane >> 4) << 4;
#pragma unroll
        for (int mt = 0; mt < 4; ++mt)
            af[mt] = *(const bf16x8*)(ldsA + (wr * 64 + mt * 16 + (lane & 15)) * 64 + kb);
#pragma unroll
        for (int nt = 0; nt < 4; ++nt)
            bfr[nt] = *(const bf16x8*)(ldsB + (wc * 64 + nt * 16 + (lane & 15)) * 64 + kb);
#pragma unroll
        for (int mt = 0; mt < 4; ++mt)
#pragma unroll
            for (int nt = 0; nt < 4; ++nt)
                acc[mt][nt] = MFMA16(af[mt], bfr[nt], acc[mt][nt]);
        __syncthreads();
    }
    // epilogue: D layout col = lane&15, row = (lane>>4)*4 + r
    const int g = lane >> 4, cl = lane & 15;
#pragma unroll
    for (int nt = 0; nt < 4; ++nt) {
        int col = col0 + wc * 64 + nt * 16 + cl;
        float bs = bias0[col];
        if (bias1) bs += bias1[col];
        if (bias2) bs += bias2[col];
#pragma unroll
        for (int mt = 0; mt < 4; ++mt) {
#pragma unroll
            for (int r = 0; r < 4; ++r) {
                int row = row0 + wr * 64 + mt * 16 + g * 4 + r;
                float v = acc[mt][nt][r] + bs;
                if (BF16OUT)
                    ((u16*)C)[(size_t)row * ldc + col] = f2bf(v);
                else
                    ((float*)C)[(size_t)row * ldc + col] = v;
            }
        }
    }
}

// ---------------- attention: one block per (b, segment, head) ---------------
// qkv rows: [8192][9216] bf16. Layer's cols: base = layer*3072 (+0/1024/2048 q/k/v), head h: +h*64.
// Writes A-buffer [8192][3072] bf16 at col = layer*1024 + h*64 + d.
template <int S>
__global__ __launch_bounds__(256) void k_attn(const u16* __restrict__ qkv,
                                              u16* __restrict__ ab, int layer) {
    constexpr int NCT = S / 16;                 // score col-tiles
    constexpr int RPW = (S == 32) ? 1 : S / 64; // row-tiles per wave
    constexpr int ACTIVE = (S == 32) ? 2 : 4;
    constexpr int KST = S / 32;                 // PV k-steps
    constexpr int VSTRIDE = 2 * S;              // bytes per VT/P row
    constexpr int VMASK = VSTRIDE / 16 - 1;

    __shared__ __align__(16) char KS[S * 128];
    __shared__ __align__(16) char VTS[64 * VSTRIDE];
    __shared__ __align__(16) char PS[S * VSTRIDE];

    const int per_b = (4096 / S) * 16;
    const int b = blockIdx.x / per_b;
    const int r0 = blockIdx.x % per_b;
    const int n = r0 >> 4, h = r0 & 15;
    const int token0 = b * 4096 + n * S;
    const int colQ = layer * 3072 + h * 64;
    const int tid = threadIdx.x, lane = tid & 63, wave = tid >> 6;

    // ---- stage K (swizzled rows) and V (transposed, swizzled) ----
    constexpr int CHUNKS = S / 32;   // 16B chunks per thread per matrix
#pragma unroll
    for (int c = 0; c < CHUNKS; ++c) {
        int lc = c * 256 + tid;
        int row = lc >> 3, off = (lc & 7) * 16;
        const char* base = (const char*)qkv + ((size_t)(token0 + row) * 9216 + colQ) * 2 + off;
        u16x8 kv = *(const u16x8*)(base + 1024 * 2);
        *(u16x8*)(KS + row * 128 + (off ^ ((row & 7) << 4))) = kv;
        u16x8 vv = *(const u16x8*)(base + 2048 * 2);
        int cb = off >> 1;
#pragma unroll
        for (int e = 0; e < 8; ++e) {
            int col = cb + e;
            *(u16*)(VTS + col * VSTRIDE + ((row * 2) ^ ((col & VMASK) << 4))) = vv[e];
        }
    }
    __syncthreads();

    // ---- S = Q K^T (Q frags straight from global) ----
    f32x4 sacc[RPW][NCT] = {};
    if (wave < ACTIVE) {
#pragma unroll
        for (int rl = 0; rl < RPW; ++rl) {
            int rt = wave * RPW + rl;
#pragma unroll
            for (int ks2 = 0; ks2 < 2; ++ks2) {
                int qrow = token0 + rt * 16 + (lane & 15);
                int kbyte = ks2 * 64 + ((lane >> 4) << 4);
                bf16x8 aq = *(const bf16x8*)((const char*)qkv +
                              ((size_t)qrow * 9216 + colQ) * 2 + kbyte);
#pragma unroll
                for (int ct = 0; ct < NCT; ++ct) {
                    int krow = ct * 16 + (lane & 15);
                    bf16x8 bk = *(const bf16x8*)(KS + krow * 128 + (kbyte ^ ((krow & 7) << 4)));
                    sacc[rl][ct] = MFMA16(aq, bk, sacc[rl][ct]);
                }
            }
        }
        // ---- softmax (rows live in D-frags: col=lane&15, row=(lane>>4)*4+r) ----
#pragma unroll
        for (int rl = 0; rl < RPW; ++rl) {
            int rt = wave * RPW + rl;
#pragma unroll
            for (int r = 0; r < 4; ++r) {
                float vals[NCT];
                float m = -1e30f;
#pragma unroll
                for (int ct = 0; ct < NCT; ++ct) {
                    vals[ct] = sacc[rl][ct][r] * 0.125f;
                    m = fmaxf(m, vals[ct]);
                }
#pragma unroll
                for (int d = 1; d < 16; d <<= 1) m = fmaxf(m, __shfl_xor(m, d, 64));
                float sum = 0.f;
#pragma unroll
                for (int ct = 0; ct < NCT; ++ct) {
                    float p = exp2f((vals[ct] - m) * 1.44269504f);
                    vals[ct] = p;
                    sum += p;
                }
#pragma unroll
                for (int d = 1; d < 16; d <<= 1) sum += __shfl_xor(sum, d, 64);
                float inv = 1.0f / sum;
                int row = rt * 16 + ((lane >> 4) << 2) + r;
#pragma unroll
                for (int ct = 0; ct < NCT; ++ct) {
                    int col = ct * 16 + (lane & 15);
                    *(u16*)(PS + row * VSTRIDE + ((col * 2) ^ ((row & VMASK) << 4))) =
                        f2bf(vals[ct] * inv);
                }
            }
        }
    }
    __syncthreads();

    // ---- O = P V ----
    if (wave < ACTIVE) {
        const int colA = layer * 1024 + h * 64;
#pragma unroll
        for (int rl = 0; rl < RPW; ++rl) {
            int rt = wave * RPW + rl;
            f32x4 oacc[4] = {};
#pragma unroll
            for (int ks2 = 0; ks2 < KST; ++ks2) {
                int kbyte = ks2 * 64 + ((lane >> 4) << 4);
                int prow = rt * 16 + (lane & 15);
                bf16x8 ap = *(const bf16x8*)(PS + prow * VSTRIDE + (kbyte ^ ((prow & VMASK) << 4)));
#pragma unroll
                for (int ct = 0; ct < 4; ++ct) {
                    int vcol = ct * 16 + (lane & 15);
                    bf16x8 bv = *(const bf16x8*)(VTS + vcol * VSTRIDE + (kbyte ^ ((vcol & VMASK) << 4)));
                    oacc[ct] = MFMA16(ap, bv, oacc[ct]);
                }
            }
#pragma unroll
            for (int ct = 0; ct < 4; ++ct) {
#pragma unroll
                for (int r = 0; r < 4; ++r) {
                    int row = token0 + rt * 16 + ((lane >> 4) << 2) + r;
                    int col = colA + ct * 16 + (lane & 15);
                    ab[(size_t)row * 3072 + col] = f2bf(oacc[ct][r]);
                }
            }
        }
    }
}

// ---------------------------------------------------------------------------
extern "C" void kernel_launch(void* const* d_in, const int* in_sizes, int n_in,
                              void* d_out, int out_size, void* d_ws, size_t ws_size,
                              hipStream_t stream) {
    const float* x    = (const float*)d_in[0];
    const float* Wqkv = (const float*)d_in[1];
    const float* bqkv = (const float*)d_in[2];
    const float* Wo   = (const float*)d_in[3];
    const float* bo   = (const float*)d_in[4];

    char* ws = (char*)d_ws;
    u16* XE    = (u16*)(ws);                       // [8192][1024]   16.8 MB
    u16* WQKVT = (u16*)(ws + 16777216);            // [9216][1024]   18.9 MB
    u16* WOT   = (u16*)(ws + 35651584);            // [1024][3072]    6.3 MB
    u16* QKVB  = (u16*)(ws + 41943040);            // [8192][9216]  151.0 MB
    u16* ABUF  = (u16*)(ws + 192937984);           // [8192][3072]   50.3 MB

    k_prep_xe<<<8192, 256, 0, stream>>>(x, XE);
    k_transpose_cast<<<dim3(16, 48, 3), 256, 0, stream>>>(
        Wqkv, WQKVT, 3072, (size_t)1024 * 3072, 1024, 3072, 0);
    k_transpose_cast<<<dim3(16, 16, 3), 256, 0, stream>>>(
        Wo, WOT, 1024, (size_t)1024 * 1024, 3072, 0, 1024);

    // QKV projection for all 3 layers: [8192,1024] @ [1024,9216]
    k_gemm_bt<true><<<dim3(64, 72), 256, 0, stream>>>(
        XE, WQKVT, QKVB, bqkv, nullptr, nullptr, 1024, 1024, 1024, 9216);

    // dilated segment attention per layer
    k_attn<32><<<4096, 256, 0, stream>>>(QKVB, ABUF, 0);
    k_attn<64><<<2048, 256, 0, stream>>>(QKVB, ABUF, 1);
    k_attn<128><<<1024, 256, 0, stream>>>(QKVB, ABUF, 2);

    // fused output projection + layer sum: [8192,3072] @ [3072,1024]
    k_gemm_bt<false><<<dim3(64, 8), 256, 0, stream>>>(
        ABUF, WOT, d_out, bo, bo + 1024, bo + 2048, 3072, 3072, 3072, 1024);
}

// Round 2
// 360.527 us; speedup vs baseline: 1.0165x; 1.0165x over previous
//
#include <hip/hip_runtime.h>
#include <hip/hip_bf16.h>
#include <stdint.h>

typedef unsigned short u16;
typedef short bf16x8 __attribute__((ext_vector_type(8)));
typedef u16   u16x8  __attribute__((ext_vector_type(8)));
typedef u16   u16x4  __attribute__((ext_vector_type(4)));
typedef float f32x4  __attribute__((ext_vector_type(4)));

__device__ inline u16 f2bf(float f) {
    uint32_t u = __builtin_bit_cast(uint32_t, f);
    uint32_t r = (u + 0x7FFFu + ((u >> 16) & 1u)) >> 16;
    return (u16)r;
}

__device__ inline void gload16(const void* g, void* l) {
    __builtin_amdgcn_global_load_lds((const __attribute__((address_space(1))) void*)g,
                                     (__attribute__((address_space(3))) void*)l, 16, 0, 0);
}

__device__ inline void pin_barrier() {
    __builtin_amdgcn_sched_barrier(0);
    __builtin_amdgcn_s_barrier();
    __builtin_amdgcn_sched_barrier(0);
}

#define MFMA16(a, b, c) __builtin_amdgcn_mfma_f32_16x16x32_bf16((a), (b), (c), 0, 0, 0)

// ---------------- prep: gather even rows of x, cast to bf16 -----------------
__global__ __launch_bounds__(256) void k_prep_xe(const float* __restrict__ x,
                                                 u16* __restrict__ xe) {
    int row = blockIdx.x;              // 0..8191
    int b = row >> 12, tt = row & 4095;
    const float* src = x + ((size_t)b * 8192 + 2 * (size_t)tt) * 1024;
    float4 v = ((const float4*)src)[threadIdx.x];
    u16x4 o = { f2bf(v.x), f2bf(v.y), f2bf(v.z), f2bf(v.w) };
    *(u16x4*)(xe + (size_t)row * 1024 + threadIdx.x * 4) = o;
}

// ---------------- prep: transpose + cast weights to B^T layout --------------
__global__ __launch_bounds__(256) void k_transpose_cast(
    const float* __restrict__ src, u16* __restrict__ dst,
    int srcCols, size_t srcLayerStride, int dstStride, int dstRowPer, int dstColPer) {
    int k0 = blockIdx.x * 64, e0 = blockIdx.y * 64, layer = blockIdx.z;
    const float* s = src + (size_t)layer * srcLayerStride;
    __shared__ u16 T[64][66];
    int t = threadIdx.x;
#pragma unroll
    for (int p = 0; p < 16; ++p) {
        int l = p * 256 + t;
        int kl = l >> 6, el = l & 63;
        T[kl][el] = f2bf(s[(size_t)(k0 + kl) * srcCols + e0 + el]);
    }
    __syncthreads();
    int rowBase = layer * dstRowPer + e0;
    int colBase = layer * dstColPer + k0;
#pragma unroll
    for (int p = 0; p < 16; ++p) {
        int l = p * 256 + t;
        int eo = l >> 6, ko = l & 63;
        dst[(size_t)(rowBase + eo) * dstStride + colBase + ko] = T[ko][eo];
    }
}

// ============ 256x256 deep-pipelined GEMM: C = A[M,K] @ BT[N,K]^T + bias ====
// BK=32, 4-deep circular LDS buffer (128KB), 2 phases/K-tile, 16 MFMA/phase,
// prefetch distance 3 K-tiles, vmcnt(8) once per tile (counted, never 0).
// st_16x32 swizzle: LDS layout byte(row,col)= (row>>4)*1024 + (row&15)*64
//                   + ((col*2) ^ (((row>>3)&1)<<5)), applied via pre-swizzled
//                   global source (linear global_load_lds dest) + swizzled read.
// Requires: K % 32 == 0, K/32 >= 3, M % 256 == 0, N % 256 == 0, grid % 8 == 0.
__global__ __launch_bounds__(512, 2) void k_gemm256(
    const u16* __restrict__ A, const u16* __restrict__ B, u16* __restrict__ C,
    const float* __restrict__ bias, int K, int lda, int ldb, int ldc,
    int gxmask, int gxshift) {
    __shared__ __align__(16) char smem[131072];
    const int tid = threadIdx.x;
    const int lane = tid & 63, wave = tid >> 6;
    const int wr = wave >> 2, wc = wave & 3;       // 2x4 wave grid

    // bijective XCD swizzle (grid multiple of 8)
    const int nwg = gridDim.x;
    const int bid = blockIdx.x;
    const int cpx = nwg >> 3;
    const int swz = (bid & 7) * cpx + (bid >> 3);
    const int bx = swz & gxmask;
    const int by = swz >> gxshift;
    const int row0 = bx << 8, col0 = by << 8;

#define SA(q) (smem + (q) * 32768)
#define SB(q) (smem + (q) * 32768 + 16384)

    // staging: chunk c (16B) -> row = (c>>6)*16 + ((c>>2)&15),
    //          colbyte = ((c&3)*16) ^ (((c>>5)&1)<<5)
    const int c0 = tid, c1 = tid + 512;
    const int rA0 = ((c0 >> 6) << 4) + ((c0 >> 2) & 15);
    const int rA1 = ((c1 >> 6) << 4) + ((c1 >> 2) & 15);
    const int cb0 = ((c0 & 3) * 16) ^ (((c0 >> 5) & 1) << 5);
    const int cb1 = ((c1 & 3) * 16) ^ (((c1 >> 5) & 1) << 5);
    const size_t lda2 = (size_t)lda * 2, ldb2 = (size_t)ldb * 2;
    const char* pA0 = (const char*)A + (size_t)(row0 + rA0) * lda2 + cb0;
    const char* pA1 = (const char*)A + (size_t)(row0 + rA1) * lda2 + cb1;
    const char* pB0 = (const char*)B + (size_t)(col0 + rA0) * ldb2 + cb0;
    const char* pB1 = (const char*)B + (size_t)(col0 + rA1) * ldb2 + cb1;
    const int ldsOff0 = wave * 1024, ldsOff1 = 8192 + wave * 1024;

#define STAGE_A(q, kof) do { gload16(pA0 + (kof), SA(q) + ldsOff0); \
                             gload16(pA1 + (kof), SA(q) + ldsOff1); } while (0)
#define STAGE_B(q, kof) do { gload16(pB0 + (kof), SB(q) + ldsOff0); \
                             gload16(pB1 + (kof), SB(q) + ldsOff1); } while (0)

    // swizzled per-lane ds_read offset (frag: row=lane&15, kbyte=(lane>>4)*16)
    const int lane_off = (lane & 15) * 64 + (((lane >> 4) << 4) ^ (((lane >> 3) & 1) << 5));

    f32x4 acc[8][4] = {};
    const int nt = K >> 5;

    // prologue: stage tiles 0,1,2 (12 loads/thread); vmcnt(8) -> tile 0 done
    STAGE_A(0, 0);   STAGE_B(0, 0);
    STAGE_A(1, 64);  STAGE_B(1, 64);
    STAGE_A(2, 128); STAGE_B(2, 128);
    __builtin_amdgcn_sched_barrier(0);
    asm volatile("s_waitcnt vmcnt(8)" ::: "memory");
    pin_barrier();

    for (int t = 0; t < nt; ++t) {
        const int q = t & 3, q3 = (t + 3) & 3;
        const int ts = (t + 3 < nt) ? (t + 3) : (nt - 1);   // clamp tail (dead buffer)
        const size_t kof = (size_t)ts * 64;
        const char* aRd = SA(q) + wr * 8192 + lane_off;
        const char* bRd = SB(q) + wc * 4096 + lane_off;

        bf16x8 af[4], bg[4];
        // ---- phase 1: quadrant mt 0-3 x nt 0-3 ----
#pragma unroll
        for (int i = 0; i < 4; ++i) af[i] = *(const bf16x8*)(aRd + i * 1024);
#pragma unroll
        for (int i = 0; i < 4; ++i) bg[i] = *(const bf16x8*)(bRd + i * 1024);
        STAGE_A(q3, kof);
        pin_barrier();
        __builtin_amdgcn_s_setprio(1);
#pragma unroll
        for (int m = 0; m < 4; ++m)
#pragma unroll
            for (int n = 0; n < 4; ++n)
                acc[m][n] = MFMA16(af[m], bg[n], acc[m][n]);
        __builtin_amdgcn_s_setprio(0);
        pin_barrier();

        // ---- phase 2: quadrant mt 4-7 x nt 0-3 ----
#pragma unroll
        for (int i = 0; i < 4; ++i) af[i] = *(const bf16x8*)(aRd + (4 + i) * 1024);
        STAGE_B(q3, kof);
        __builtin_amdgcn_sched_barrier(0);
        asm volatile("s_waitcnt vmcnt(8)" ::: "memory");   // tile t+1 complete
        pin_barrier();
        __builtin_amdgcn_s_setprio(1);
#pragma unroll
        for (int m = 0; m < 4; ++m)
#pragma unroll
            for (int n = 0; n < 4; ++n)
                acc[4 + m][n] = MFMA16(af[m], bg[n], acc[4 + m][n]);
        __builtin_amdgcn_s_setprio(0);
        pin_barrier();
    }

    // epilogue: D layout col=lane&15 (N), row=(lane>>4)*4+r (M)
    const int g4 = (lane >> 4) << 2, cl = lane & 15;
#pragma unroll
    for (int n = 0; n < 4; ++n) {
        int col = col0 + wc * 64 + n * 16 + cl;
        float bs = bias[col];
#pragma unroll
        for (int m = 0; m < 8; ++m) {
#pragma unroll
            for (int r = 0; r < 4; ++r) {
                int row = row0 + wr * 128 + m * 16 + g4 + r;
                C[(size_t)row * ldc + col] = f2bf(acc[m][n][r] + bs);
            }
        }
    }
#undef SA
#undef SB
#undef STAGE_A
#undef STAGE_B
}

// ---------------- GEMM (m97 structure) for the output projection ------------
template <bool BF16OUT>
__global__ __launch_bounds__(256) void k_gemm_bt(
    const u16* __restrict__ A, const u16* __restrict__ B, void* __restrict__ C,
    const float* __restrict__ bias0, const float* __restrict__ bias1,
    const float* __restrict__ bias2, int K, int lda, int ldb, int ldc) {
    __shared__ __align__(16) char smem[16384];   // As 8KB | Bs 8KB
    const int tid = threadIdx.x;
    const int lane = tid & 63, wave = tid >> 6;
    const int wr = wave >> 1, wc = wave & 1;
    const int row0 = blockIdx.x * 128, col0 = blockIdx.y * 128;
    f32x4 acc[4][4] = {};
    const int nk = K >> 5;
    const char* Abase = (const char*)(A + (size_t)row0 * lda);
    const char* Bbase = (const char*)(B + (size_t)col0 * ldb);
    char* ldsA = smem;
    char* ldsB = smem + 8192;
    const size_t lda2 = (size_t)lda * 2, ldb2 = (size_t)ldb * 2;
    const int c0 = tid;
    const int c1 = tid + 256;

    for (int ks = 0; ks < nk; ++ks) {
        const size_t kb0 = (size_t)(ks * 32) * 2;
        gload16(Abase + (size_t)(c0 >> 2) * lda2 + kb0 + (c0 & 3) * 16, ldsA + wave * 1024);
        gload16(Abase + (size_t)(c1 >> 2) * lda2 + kb0 + (c1 & 3) * 16, ldsA + 4096 + wave * 1024);
        gload16(Bbase + (size_t)(c0 >> 2) * ldb2 + kb0 + (c0 & 3) * 16, ldsB + wave * 1024);
        gload16(Bbase + (size_t)(c1 >> 2) * ldb2 + kb0 + (c1 & 3) * 16, ldsB + 4096 + wave * 1024);
        __syncthreads();
        bf16x8 af[4], bfr[4];
        const int kb = (lane >> 4) << 4;
#pragma unroll
        for (int mt = 0; mt < 4; ++mt)
            af[mt] = *(const bf16x8*)(ldsA + (wr * 64 + mt * 16 + (lane & 15)) * 64 + kb);
#pragma unroll
        for (int nt = 0; nt < 4; ++nt)
            bfr[nt] = *(const bf16x8*)(ldsB + (wc * 64 + nt * 16 + (lane & 15)) * 64 + kb);
#pragma unroll
        for (int mt = 0; mt < 4; ++mt)
#pragma unroll
            for (int nt = 0; nt < 4; ++nt)
                acc[mt][nt] = MFMA16(af[mt], bfr[nt], acc[mt][nt]);
        __syncthreads();
    }
    const int g = lane >> 4, cl = lane & 15;
#pragma unroll
    for (int nt = 0; nt < 4; ++nt) {
        int col = col0 + wc * 64 + nt * 16 + cl;
        float bs = bias0[col];
        if (bias1) bs += bias1[col];
        if (bias2) bs += bias2[col];
#pragma unroll
        for (int mt = 0; mt < 4; ++mt) {
#pragma unroll
            for (int r = 0; r < 4; ++r) {
                int row = row0 + wr * 64 + mt * 16 + g * 4 + r;
                float v = acc[mt][nt][r] + bs;
                if (BF16OUT)
                    ((u16*)C)[(size_t)row * ldc + col] = f2bf(v);
                else
                    ((float*)C)[(size_t)row * ldc + col] = v;
            }
        }
    }
}

// ---------------- attention: one block per (b, segment, head) ---------------
template <int S>
__global__ __launch_bounds__(256) void k_attn(const u16* __restrict__ qkv,
                                              u16* __restrict__ ab, int layer) {
    constexpr int NCT = S / 16;
    constexpr int RPW = (S == 32) ? 1 : S / 64;
    constexpr int ACTIVE = (S == 32) ? 2 : 4;
    constexpr int KST = S / 32;
    constexpr int VSTRIDE = 2 * S;
    constexpr int VMASK = VSTRIDE / 16 - 1;

    __shared__ __align__(16) char KS[S * 128];
    __shared__ __align__(16) char VTS[64 * VSTRIDE];
    __shared__ __align__(16) char PS[S * VSTRIDE];

    const int per_b = (4096 / S) * 16;
    const int b = blockIdx.x / per_b;
    const int r0 = blockIdx.x % per_b;
    const int n = r0 >> 4, h = r0 & 15;
    const int token0 = b * 4096 + n * S;
    const int colQ = layer * 3072 + h * 64;
    const int tid = threadIdx.x, lane = tid & 63, wave = tid >> 6;

    constexpr int CHUNKS = S / 32;
#pragma unroll
    for (int c = 0; c < CHUNKS; ++c) {
        int lc = c * 256 + tid;
        int row = lc >> 3, off = (lc & 7) * 16;
        const char* base = (const char*)qkv + ((size_t)(token0 + row) * 9216 + colQ) * 2 + off;
        u16x8 kv = *(const u16x8*)(base + 1024 * 2);
        *(u16x8*)(KS + row * 128 + (off ^ ((row & 7) << 4))) = kv;
        u16x8 vv = *(const u16x8*)(base + 2048 * 2);
        int cb = off >> 1;
#pragma unroll
        for (int e = 0; e < 8; ++e) {
            int col = cb + e;
            *(u16*)(VTS + col * VSTRIDE + ((row * 2) ^ ((col & VMASK) << 4))) = vv[e];
        }
    }
    __syncthreads();

    f32x4 sacc[RPW][NCT] = {};
    if (wave < ACTIVE) {
#pragma unroll
        for (int rl = 0; rl < RPW; ++rl) {
            int rt = wave * RPW + rl;
#pragma unroll
            for (int ks2 = 0; ks2 < 2; ++ks2) {
                int qrow = token0 + rt * 16 + (lane & 15);
                int kbyte = ks2 * 64 + ((lane >> 4) << 4);
                bf16x8 aq = *(const bf16x8*)((const char*)qkv +
                              ((size_t)qrow * 9216 + colQ) * 2 + kbyte);
#pragma unroll
                for (int ct = 0; ct < NCT; ++ct) {
                    int krow = ct * 16 + (lane & 15);
                    bf16x8 bk = *(const bf16x8*)(KS + krow * 128 + (kbyte ^ ((krow & 7) << 4)));
                    sacc[rl][ct] = MFMA16(aq, bk, sacc[rl][ct]);
                }
            }
        }
#pragma unroll
        for (int rl = 0; rl < RPW; ++rl) {
            int rt = wave * RPW + rl;
#pragma unroll
            for (int r = 0; r < 4; ++r) {
                float vals[NCT];
                float m = -1e30f;
#pragma unroll
                for (int ct = 0; ct < NCT; ++ct) {
                    vals[ct] = sacc[rl][ct][r] * 0.125f;
                    m = fmaxf(m, vals[ct]);
                }
#pragma unroll
                for (int d = 1; d < 16; d <<= 1) m = fmaxf(m, __shfl_xor(m, d, 64));
                float sum = 0.f;
#pragma unroll
                for (int ct = 0; ct < NCT; ++ct) {
                    float p = exp2f((vals[ct] - m) * 1.44269504f);
                    vals[ct] = p;
                    sum += p;
                }
#pragma unroll
                for (int d = 1; d < 16; d <<= 1) sum += __shfl_xor(sum, d, 64);
                float inv = 1.0f / sum;
                int row = rt * 16 + ((lane >> 4) << 2) + r;
#pragma unroll
                for (int ct = 0; ct < NCT; ++ct) {
                    int col = ct * 16 + (lane & 15);
                    *(u16*)(PS + row * VSTRIDE + ((col * 2) ^ ((row & VMASK) << 4))) =
                        f2bf(vals[ct] * inv);
                }
            }
        }
    }
    __syncthreads();

    if (wave < ACTIVE) {
        const int colA = layer * 1024 + h * 64;
#pragma unroll
        for (int rl = 0; rl < RPW; ++rl) {
            int rt = wave * RPW + rl;
            f32x4 oacc[4] = {};
#pragma unroll
            for (int ks2 = 0; ks2 < KST; ++ks2) {
                int kbyte = ks2 * 64 + ((lane >> 4) << 4);
                int prow = rt * 16 + (lane & 15);
                bf16x8 ap = *(const bf16x8*)(PS + prow * VSTRIDE + (kbyte ^ ((prow & VMASK) << 4)));
#pragma unroll
                for (int ct = 0; ct < 4; ++ct) {
                    int vcol = ct * 16 + (lane & 15);
                    bf16x8 bv = *(const bf16x8*)(VTS + vcol * VSTRIDE + (kbyte ^ ((vcol & VMASK) << 4)));
                    oacc[ct] = MFMA16(ap, bv, oacc[ct]);
                }
            }
#pragma unroll
            for (int ct = 0; ct < 4; ++ct) {
#pragma unroll
                for (int r = 0; r < 4; ++r) {
                    int row = token0 + rt * 16 + ((lane >> 4) << 2) + r;
                    int col = colA + ct * 16 + (lane & 15);
                    ab[(size_t)row * 3072 + col] = f2bf(oacc[ct][r]);
                }
            }
        }
    }
}

// ---------------------------------------------------------------------------
extern "C" void kernel_launch(void* const* d_in, const int* in_sizes, int n_in,
                              void* d_out, int out_size, void* d_ws, size_t ws_size,
                              hipStream_t stream) {
    const float* x    = (const float*)d_in[0];
    const float* Wqkv = (const float*)d_in[1];
    const float* bqkv = (const float*)d_in[2];
    const float* Wo   = (const float*)d_in[3];
    const float* bo   = (const float*)d_in[4];

    char* ws = (char*)d_ws;
    u16* XE    = (u16*)(ws);                       // [8192][1024]
    u16* WQKVT = (u16*)(ws + 16777216);            // [9216][1024]
    u16* WOT   = (u16*)(ws + 35651584);            // [1024][3072]
    u16* QKVB  = (u16*)(ws + 41943040);            // [8192][9216]
    u16* ABUF  = (u16*)(ws + 192937984);           // [8192][3072]

    k_prep_xe<<<8192, 256, 0, stream>>>(x, XE);
    k_transpose_cast<<<dim3(16, 48, 3), 256, 0, stream>>>(
        Wqkv, WQKVT, 3072, (size_t)1024 * 3072, 1024, 3072, 0);
    k_transpose_cast<<<dim3(16, 16, 3), 256, 0, stream>>>(
        Wo, WOT, 1024, (size_t)1024 * 1024, 3072, 0, 1024);

    // QKV projection for all 3 layers: [8192,1024] @ [1024,9216]
    // grid = 32 x 36 = 1152 blocks (bx fastest, GX=32 -> mask 31, shift 5)
    k_gemm256<<<dim3(1152), 512, 0, stream>>>(
        XE, WQKVT, QKVB, bqkv, 1024, 1024, 1024, 9216, 31, 5);

    // dilated segment attention per layer
    k_attn<32><<<4096, 256, 0, stream>>>(QKVB, ABUF, 0);
    k_attn<64><<<2048, 256, 0, stream>>>(QKVB, ABUF, 1);
    k_attn<128><<<1024, 256, 0, stream>>>(QKVB, ABUF, 2);

    // fused output projection + layer sum: [8192,3072] @ [3072,1024]
    k_gemm_bt<false><<<dim3(64, 8), 256, 0, stream>>>(
        ABUF, WOT, d_out, bo, bo + 1024, bo + 2048, 3072, 3072, 3072, 1024);
}

// Round 3
// 345.368 us; speedup vs baseline: 1.0611x; 1.0439x over previous
//
#include <hip/hip_runtime.h>
#include <hip/hip_bf16.h>
#include <stdint.h>

typedef unsigned short u16;
typedef short bf16x8 __attribute__((ext_vector_type(8)));
typedef u16   u16x8  __attribute__((ext_vector_type(8)));
typedef u16   u16x4  __attribute__((ext_vector_type(4)));
typedef float f32x4  __attribute__((ext_vector_type(4)));

__device__ inline u16 f2bf(float f) {
    uint32_t u = __builtin_bit_cast(uint32_t, f);
    uint32_t r = (u + 0x7FFFu + ((u >> 16) & 1u)) >> 16;
    return (u16)r;
}

__device__ inline void gload16(const void* g, void* l) {
    __builtin_amdgcn_global_load_lds((const __attribute__((address_space(1))) void*)g,
                                     (__attribute__((address_space(3))) void*)l, 16, 0, 0);
}

__device__ inline void pin_barrier() {
    __builtin_amdgcn_sched_barrier(0);
    __builtin_amdgcn_s_barrier();
    __builtin_amdgcn_sched_barrier(0);
}

#define MFMA16(a, b, c) __builtin_amdgcn_mfma_f32_16x16x32_bf16((a), (b), (c), 0, 0, 0)

// ---------------- prep: gather even rows of x, cast to bf16 -----------------
__global__ __launch_bounds__(256) void k_prep_xe(const float* __restrict__ x,
                                                 u16* __restrict__ xe) {
    int row = blockIdx.x;              // 0..8191
    int b = row >> 12, tt = row & 4095;
    const float* src = x + ((size_t)b * 8192 + 2 * (size_t)tt) * 1024;
    float4 v = ((const float4*)src)[threadIdx.x];
    u16x4 o = { f2bf(v.x), f2bf(v.y), f2bf(v.z), f2bf(v.w) };
    *(u16x4*)(xe + (size_t)row * 1024 + threadIdx.x * 4) = o;
}

// ---------------- prep: transpose + cast weights to B^T layout --------------
__global__ __launch_bounds__(256) void k_transpose_cast(
    const float* __restrict__ src, u16* __restrict__ dst,
    int srcCols, size_t srcLayerStride, int dstStride, int dstRowPer, int dstColPer) {
    int k0 = blockIdx.x * 64, e0 = blockIdx.y * 64, layer = blockIdx.z;
    const float* s = src + (size_t)layer * srcLayerStride;
    __shared__ u16 T[64][66];
    int t = threadIdx.x;
#pragma unroll
    for (int p = 0; p < 16; ++p) {
        int l = p * 256 + t;
        int kl = l >> 6, el = l & 63;
        T[kl][el] = f2bf(s[(size_t)(k0 + kl) * srcCols + e0 + el]);
    }
    __syncthreads();
    int rowBase = layer * dstRowPer + e0;
    int colBase = layer * dstColPer + k0;
#pragma unroll
    for (int p = 0; p < 16; ++p) {
        int l = p * 256 + t;
        int eo = l >> 6, ko = l & 63;
        dst[(size_t)(rowBase + eo) * dstStride + colBase + ko] = T[ko][eo];
    }
}

// ============ 256x256 deep-pipelined GEMM: C = A[M,K] @ BT[N,K]^T + bias ====
// BK=32, 4-deep circular LDS buffer (128KB), 2 phases/K-tile, 16 MFMA/phase,
// prefetch distance 3 K-tiles, vmcnt(8) once per tile (counted, never 0).
// Epilogue: LDS-restaged coalesced bf16 stores (full-line writes, no RMW).
// Requires: K % 32 == 0, K/32 >= 3, M % 256 == 0, N % 256 == 0, grid % 8 == 0.
__global__ __launch_bounds__(512, 2) void k_gemm256(
    const u16* __restrict__ A, const u16* __restrict__ B, u16* __restrict__ C,
    const float* __restrict__ bias, int K, int lda, int ldb, int ldc,
    int gxmask, int gxshift) {
    __shared__ __align__(16) char smem[131072];
    const int tid = threadIdx.x;
    const int lane = tid & 63, wave = tid >> 6;
    const int wr = wave >> 2, wc = wave & 3;       // 2x4 wave grid

    // bijective XCD swizzle (grid multiple of 8)
    const int nwg = gridDim.x;
    const int bid = blockIdx.x;
    const int cpx = nwg >> 3;
    const int swz = (bid & 7) * cpx + (bid >> 3);
    const int bx = swz & gxmask;
    const int by = swz >> gxshift;
    const int row0 = bx << 8, col0 = by << 8;

#define SA(q) (smem + (q) * 32768)
#define SB(q) (smem + (q) * 32768 + 16384)

    // staging: chunk c (16B) -> row = (c>>6)*16 + ((c>>2)&15),
    //          colbyte = ((c&3)*16) ^ (((c>>5)&1)<<5)
    const int c0 = tid, c1 = tid + 512;
    const int rA0 = ((c0 >> 6) << 4) + ((c0 >> 2) & 15);
    const int rA1 = ((c1 >> 6) << 4) + ((c1 >> 2) & 15);
    const int cb0 = ((c0 & 3) * 16) ^ (((c0 >> 5) & 1) << 5);
    const int cb1 = ((c1 & 3) * 16) ^ (((c1 >> 5) & 1) << 5);
    const size_t lda2 = (size_t)lda * 2, ldb2 = (size_t)ldb * 2;
    const char* pA0 = (const char*)A + (size_t)(row0 + rA0) * lda2 + cb0;
    const char* pA1 = (const char*)A + (size_t)(row0 + rA1) * lda2 + cb1;
    const char* pB0 = (const char*)B + (size_t)(col0 + rA0) * ldb2 + cb0;
    const char* pB1 = (const char*)B + (size_t)(col0 + rA1) * ldb2 + cb1;
    const int ldsOff0 = wave * 1024, ldsOff1 = 8192 + wave * 1024;

#define STAGE_A(q, kof) do { gload16(pA0 + (kof), SA(q) + ldsOff0); \
                             gload16(pA1 + (kof), SA(q) + ldsOff1); } while (0)
#define STAGE_B(q, kof) do { gload16(pB0 + (kof), SB(q) + ldsOff0); \
                             gload16(pB1 + (kof), SB(q) + ldsOff1); } while (0)

    // swizzled per-lane ds_read offset (frag: row=lane&15, kbyte=(lane>>4)*16)
    const int lane_off = (lane & 15) * 64 + (((lane >> 4) << 4) ^ (((lane >> 3) & 1) << 5));

    f32x4 acc[8][4] = {};
    const int nt = K >> 5;

    // prologue: stage tiles 0,1,2 (12 loads/thread); vmcnt(8) -> tile 0 done
    STAGE_A(0, 0);   STAGE_B(0, 0);
    STAGE_A(1, 64);  STAGE_B(1, 64);
    STAGE_A(2, 128); STAGE_B(2, 128);
    __builtin_amdgcn_sched_barrier(0);
    asm volatile("s_waitcnt vmcnt(8)" ::: "memory");
    pin_barrier();

    for (int t = 0; t < nt; ++t) {
        const int q = t & 3, q3 = (t + 3) & 3;
        const int ts = (t + 3 < nt) ? (t + 3) : (nt - 1);   // clamp tail (dead buffer)
        const size_t kof = (size_t)ts * 64;
        const char* aRd = SA(q) + wr * 8192 + lane_off;
        const char* bRd = SB(q) + wc * 4096 + lane_off;

        bf16x8 af[4], bg[4];
        // ---- phase 1: quadrant mt 0-3 x nt 0-3 ----
#pragma unroll
        for (int i = 0; i < 4; ++i) af[i] = *(const bf16x8*)(aRd + i * 1024);
#pragma unroll
        for (int i = 0; i < 4; ++i) bg[i] = *(const bf16x8*)(bRd + i * 1024);
        STAGE_A(q3, kof);
        pin_barrier();
        __builtin_amdgcn_s_setprio(1);
#pragma unroll
        for (int m = 0; m < 4; ++m)
#pragma unroll
            for (int n = 0; n < 4; ++n)
                acc[m][n] = MFMA16(af[m], bg[n], acc[m][n]);
        __builtin_amdgcn_s_setprio(0);
        pin_barrier();

        // ---- phase 2: quadrant mt 4-7 x nt 0-3 ----
#pragma unroll
        for (int i = 0; i < 4; ++i) af[i] = *(const bf16x8*)(aRd + (4 + i) * 1024);
        STAGE_B(q3, kof);
        __builtin_amdgcn_sched_barrier(0);
        asm volatile("s_waitcnt vmcnt(8)" ::: "memory");   // tile t+1 complete
        pin_barrier();
        __builtin_amdgcn_s_setprio(1);
#pragma unroll
        for (int m = 0; m < 4; ++m)
#pragma unroll
            for (int n = 0; n < 4; ++n)
                acc[4 + m][n] = MFMA16(af[m], bg[n], acc[4 + m][n]);
        __builtin_amdgcn_s_setprio(0);
        pin_barrier();
    }

    // ---- epilogue: LDS-restage to get full-cache-line coalesced stores ----
    // LDS tile: [256 rows][256 cols] bf16 (512 B/row). Chunk = 8 u16 = 16 B.
    // Swizzle: chunk index ^= (row>>2)&3  (per-ds_write, the 4 lane-groups
    // have distinct (row>>2)&3 -> disjoint bank octets -> conflict-free).
    {
        u16* cst = (u16*)smem;
        const int g4 = (lane >> 4) << 2, cl = lane & 15;
        // all waves are past the K-loop's final barrier; LDS is reusable,
        // but in-flight dead prefetches may still land -> drain first.
        __builtin_amdgcn_sched_barrier(0);
        asm volatile("s_waitcnt vmcnt(0)" ::: "memory");
        pin_barrier();
#pragma unroll
        for (int n = 0; n < 4; ++n) {
            int col = wc * 64 + n * 16 + cl;
            float bs = bias[col0 + col];
#pragma unroll
            for (int m = 0; m < 8; ++m) {
#pragma unroll
                for (int r = 0; r < 4; ++r) {
                    int row = wr * 128 + m * 16 + g4 + r;
                    int scol = col ^ (((row >> 2) & 3) << 3);
                    cst[row * 256 + scol] = f2bf(acc[m][n][r] + bs);
                }
            }
        }
        pin_barrier();
#pragma unroll
        for (int it = 0; it < 16; ++it) {
            int id = it * 512 + tid;          // 16B-chunk id: row*32 + c16
            int row = id >> 5, c16 = id & 5 * 6 + 1; // placeholder avoided below
            c16 = id & 31;
            int sc16 = c16 ^ ((row >> 2) & 3);
            u16x8 v = *(const u16x8*)(cst + row * 256 + sc16 * 8);
            *(u16x8*)(C + (size_t)(row0 + row) * ldc + col0 + c16 * 8) = v;
        }
    }
#undef SA
#undef SB
#undef STAGE_A
#undef STAGE_B
}

// ---------------- GEMM (m97 structure) for the output projection ------------
template <bool BF16OUT>
__global__ __launch_bounds__(256) void k_gemm_bt(
    const u16* __restrict__ A, const u16* __restrict__ B, void* __restrict__ C,
    const float* __restrict__ bias0, const float* __restrict__ bias1,
    const float* __restrict__ bias2, int K, int lda, int ldb, int ldc) {
    __shared__ __align__(16) char smem[16384];   // As 8KB | Bs 8KB
    const int tid = threadIdx.x;
    const int lane = tid & 63, wave = tid >> 6;
    const int wr = wave >> 1, wc = wave & 1;
    const int row0 = blockIdx.x * 128, col0 = blockIdx.y * 128;
    f32x4 acc[4][4] = {};
    const int nk = K >> 5;
    const char* Abase = (const char*)(A + (size_t)row0 * lda);
    const char* Bbase = (const char*)(B + (size_t)col0 * ldb);
    char* ldsA = smem;
    char* ldsB = smem + 8192;
    const size_t lda2 = (size_t)lda * 2, ldb2 = (size_t)ldb * 2;
    const int c0 = tid;
    const int c1 = tid + 256;

    for (int ks = 0; ks < nk; ++ks) {
        const size_t kb0 = (size_t)(ks * 32) * 2;
        gload16(Abase + (size_t)(c0 >> 2) * lda2 + kb0 + (c0 & 3) * 16, ldsA + wave * 1024);
        gload16(Abase + (size_t)(c1 >> 2) * lda2 + kb0 + (c1 & 3) * 16, ldsA + 4096 + wave * 1024);
        gload16(Bbase + (size_t)(c0 >> 2) * ldb2 + kb0 + (c0 & 3) * 16, ldsB + wave * 1024);
        gload16(Bbase + (size_t)(c1 >> 2) * ldb2 + kb0 + (c1 & 3) * 16, ldsB + 4096 + wave * 1024);
        __syncthreads();
        bf16x8 af[4], bfr[4];
        const int kb = (lane >> 4) << 4;
#pragma unroll
        for (int mt = 0; mt < 4; ++mt)
            af[mt] = *(const bf16x8*)(ldsA + (wr * 64 + mt * 16 + (lane & 15)) * 64 + kb);
#pragma unroll
        for (int nt = 0; nt < 4; ++nt)
            bfr[nt] = *(const bf16x8*)(ldsB + (wc * 64 + nt * 16 + (lane & 15)) * 64 + kb);
#pragma unroll
        for (int mt = 0; mt < 4; ++mt)
#pragma unroll
            for (int nt = 0; nt < 4; ++nt)
                acc[mt][nt] = MFMA16(af[mt], bfr[nt], acc[mt][nt]);
        __syncthreads();
    }
    const int g = lane >> 4, cl = lane & 15;
#pragma unroll
    for (int nt = 0; nt < 4; ++nt) {
        int col = col0 + wc * 64 + nt * 16 + cl;
        float bs = bias0[col];
        if (bias1) bs += bias1[col];
        if (bias2) bs += bias2[col];
#pragma unroll
        for (int mt = 0; mt < 4; ++mt) {
#pragma unroll
            for (int r = 0; r < 4; ++r) {
                int row = row0 + wr * 64 + mt * 16 + g * 4 + r;
                float v = acc[mt][nt][r] + bs;
                if (BF16OUT)
                    ((u16*)C)[(size_t)row * ldc + col] = f2bf(v);
                else
                    ((float*)C)[(size_t)row * ldc + col] = v;
            }
        }
    }
}

// ---------------- attention: one block per (b, segment, head) ---------------
template <int S>
__global__ __launch_bounds__(256) void k_attn(const u16* __restrict__ qkv,
                                              u16* __restrict__ ab, int layer) {
    constexpr int NCT = S / 16;
    constexpr int RPW = (S == 32) ? 1 : S / 64;
    constexpr int ACTIVE = (S == 32) ? 2 : 4;
    constexpr int KST = S / 32;
    constexpr int VSTRIDE = 2 * S;
    constexpr int VMASK = VSTRIDE / 16 - 1;

    __shared__ __align__(16) char KS[S * 128];
    __shared__ __align__(16) char VTS[64 * VSTRIDE];
    __shared__ __align__(16) char PS[S * VSTRIDE];

    const int per_b = (4096 / S) * 16;
    const int b = blockIdx.x / per_b;
    const int r0 = blockIdx.x % per_b;
    const int n = r0 >> 4, h = r0 & 15;
    const int token0 = b * 4096 + n * S;
    const int colQ = layer * 3072 + h * 64;
    const int tid = threadIdx.x, lane = tid & 63, wave = tid >> 6;

    constexpr int CHUNKS = S / 32;
#pragma unroll
    for (int c = 0; c < CHUNKS; ++c) {
        int lc = c * 256 + tid;
        int row = lc >> 3, off = (lc & 7) * 16;
        const char* base = (const char*)qkv + ((size_t)(token0 + row) * 9216 + colQ) * 2 + off;
        u16x8 kv = *(const u16x8*)(base + 1024 * 2);
        *(u16x8*)(KS + row * 128 + (off ^ ((row & 7) << 4))) = kv;
        u16x8 vv = *(const u16x8*)(base + 2048 * 2);
        int cb = off >> 1;
#pragma unroll
        for (int e = 0; e < 8; ++e) {
            int col = cb + e;
            *(u16*)(VTS + col * VSTRIDE + ((row * 2) ^ ((col & VMASK) << 4))) = vv[e];
        }
    }
    __syncthreads();

    f32x4 sacc[RPW][NCT] = {};
    if (wave < ACTIVE) {
#pragma unroll
        for (int rl = 0; rl < RPW; ++rl) {
            int rt = wave * RPW + rl;
#pragma unroll
            for (int ks2 = 0; ks2 < 2; ++ks2) {
                int qrow = token0 + rt * 16 + (lane & 15);
                int kbyte = ks2 * 64 + ((lane >> 4) << 4);
                bf16x8 aq = *(const bf16x8*)((const char*)qkv +
                              ((size_t)qrow * 9216 + colQ) * 2 + kbyte);
#pragma unroll
                for (int ct = 0; ct < NCT; ++ct) {
                    int krow = ct * 16 + (lane & 15);
                    bf16x8 bk = *(const bf16x8*)(KS + krow * 128 + (kbyte ^ ((krow & 7) << 4)));
                    sacc[rl][ct] = MFMA16(aq, bk, sacc[rl][ct]);
                }
            }
        }
#pragma unroll
        for (int rl = 0; rl < RPW; ++rl) {
            int rt = wave * RPW + rl;
#pragma unroll
            for (int r = 0; r < 4; ++r) {
                float vals[NCT];
                float m = -1e30f;
#pragma unroll
                for (int ct = 0; ct < NCT; ++ct) {
                    vals[ct] = sacc[rl][ct][r] * 0.125f;
                    m = fmaxf(m, vals[ct]);
                }
#pragma unroll
                for (int d = 1; d < 16; d <<= 1) m = fmaxf(m, __shfl_xor(m, d, 64));
                float sum = 0.f;
#pragma unroll
                for (int ct = 0; ct < NCT; ++ct) {
                    float p = exp2f((vals[ct] - m) * 1.44269504f);
                    vals[ct] = p;
                    sum += p;
                }
#pragma unroll
                for (int d = 1; d < 16; d <<= 1) sum += __shfl_xor(sum, d, 64);
                float inv = 1.0f / sum;
                int row = rt * 16 + ((lane >> 4) << 2) + r;
#pragma unroll
                for (int ct = 0; ct < NCT; ++ct) {
                    int col = ct * 16 + (lane & 15);
                    *(u16*)(PS + row * VSTRIDE + ((col * 2) ^ ((row & VMASK) << 4))) =
                        f2bf(vals[ct] * inv);
                }
            }
        }
    }
    __syncthreads();

    if (wave < ACTIVE) {
        const int colA = layer * 1024 + h * 64;
#pragma unroll
        for (int rl = 0; rl < RPW; ++rl) {
            int rt = wave * RPW + rl;
            f32x4 oacc[4] = {};
#pragma unroll
            for (int ks2 = 0; ks2 < KST; ++ks2) {
                int kbyte = ks2 * 64 + ((lane >> 4) << 4);
                int prow = rt * 16 + (lane & 15);
                bf16x8 ap = *(const bf16x8*)(PS + prow * VSTRIDE + (kbyte ^ ((prow & VMASK) << 4)));
#pragma unroll
                for (int ct = 0; ct < 4; ++ct) {
                    int vcol = ct * 16 + (lane & 15);
                    bf16x8 bv = *(const bf16x8*)(VTS + vcol * VSTRIDE + (kbyte ^ ((vcol & VMASK) << 4)));
                    oacc[ct] = MFMA16(ap, bv, oacc[ct]);
                }
            }
#pragma unroll
            for (int ct = 0; ct < 4; ++ct) {
#pragma unroll
                for (int r = 0; r < 4; ++r) {
                    int row = token0 + rt * 16 + ((lane >> 4) << 2) + r;
                    int col = colA + ct * 16 + (lane & 15);
                    ab[(size_t)row * 3072 + col] = f2bf(oacc[ct][r]);
                }
            }
        }
    }
}

// ---------------------------------------------------------------------------
extern "C" void kernel_launch(void* const* d_in, const int* in_sizes, int n_in,
                              void* d_out, int out_size, void* d_ws, size_t ws_size,
                              hipStream_t stream) {
    const float* x    = (const float*)d_in[0];
    const float* Wqkv = (const float*)d_in[1];
    const float* bqkv = (const float*)d_in[2];
    const float* Wo   = (const float*)d_in[3];
    const float* bo   = (const float*)d_in[4];

    char* ws = (char*)d_ws;
    u16* XE    = (u16*)(ws);                       // [8192][1024]
    u16* WQKVT = (u16*)(ws + 16777216);            // [9216][1024]
    u16* WOT   = (u16*)(ws + 35651584);            // [1024][3072]
    u16* QKVB  = (u16*)(ws + 41943040);            // [8192][9216]
    u16* ABUF  = (u16*)(ws + 192937984);           // [8192][3072]

    k_prep_xe<<<8192, 256, 0, stream>>>(x, XE);
    k_transpose_cast<<<dim3(16, 48, 3), 256, 0, stream>>>(
        Wqkv, WQKVT, 3072, (size_t)1024 * 3072, 1024, 3072, 0);
    k_transpose_cast<<<dim3(16, 16, 3), 256, 0, stream>>>(
        Wo, WOT, 1024, (size_t)1024 * 1024, 3072, 0, 1024);

    // QKV projection for all 3 layers: [8192,1024] @ [1024,9216]
    // grid = 32 x 36 = 1152 blocks (bx fastest, GX=32 -> mask 31, shift 5)
    k_gemm256<<<dim3(1152), 512, 0, stream>>>(
        XE, WQKVT, QKVB, bqkv, 1024, 1024, 1024, 9216, 31, 5);

    // dilated segment attention per layer
    k_attn<32><<<4096, 256, 0, stream>>>(QKVB, ABUF, 0);
    k_attn<64><<<2048, 256, 0, stream>>>(QKVB, ABUF, 1);
    k_attn<128><<<1024, 256, 0, stream>>>(QKVB, ABUF, 2);

    // fused output projection + layer sum: [8192,3072] @ [3072,1024]
    k_gemm_bt<false><<<dim3(64, 8), 256, 0, stream>>>(
        ABUF, WOT, d_out, bo, bo + 1024, bo + 2048, 3072, 3072, 3072, 1024);
}

// Round 4
// 327.878 us; speedup vs baseline: 1.1177x; 1.0533x over previous
//
#include <hip/hip_runtime.h>
#include <hip/hip_bf16.h>
#include <stdint.h>

typedef unsigned short u16;
typedef short bf16x8 __attribute__((ext_vector_type(8)));
typedef u16   u16x8  __attribute__((ext_vector_type(8)));
typedef u16   u16x4  __attribute__((ext_vector_type(4)));
typedef float f32x4  __attribute__((ext_vector_type(4)));

__device__ inline u16 f2bf(float f) {
    uint32_t u = __builtin_bit_cast(uint32_t, f);
    uint32_t r = (u + 0x7FFFu + ((u >> 16) & 1u)) >> 16;
    return (u16)r;
}

__device__ inline void pin_barrier() {
    __builtin_amdgcn_sched_barrier(0);
    __builtin_amdgcn_s_barrier();
    __builtin_amdgcn_sched_barrier(0);
}

#define MFMA16(a, b, c) __builtin_amdgcn_mfma_f32_16x16x32_bf16((a), (b), (c), 0, 0, 0)

// ---------------- prep: gather even rows of x, cast to bf16 -----------------
__global__ __launch_bounds__(256) void k_prep_xe(const float* __restrict__ x,
                                                 u16* __restrict__ xe) {
    int row = blockIdx.x;              // 0..8191
    int b = row >> 12, tt = row & 4095;
    const float* src = x + ((size_t)b * 8192 + 2 * (size_t)tt) * 1024;
    float4 v = ((const float4*)src)[threadIdx.x];
    u16x4 o = { f2bf(v.x), f2bf(v.y), f2bf(v.z), f2bf(v.w) };
    *(u16x4*)(xe + (size_t)row * 1024 + threadIdx.x * 4) = o;
}

// ---------------- prep: transpose + cast weights to B^T layout --------------
__global__ __launch_bounds__(256) void k_transpose_cast(
    const float* __restrict__ src, u16* __restrict__ dst,
    int srcCols, size_t srcLayerStride, int dstStride, int dstRowPer, int dstColPer) {
    int k0 = blockIdx.x * 64, e0 = blockIdx.y * 64, layer = blockIdx.z;
    const float* s = src + (size_t)layer * srcLayerStride;
    __shared__ u16 T[64][66];
    int t = threadIdx.x;
#pragma unroll
    for (int p = 0; p < 16; ++p) {
        int l = p * 256 + t;
        int kl = l >> 6, el = l & 63;
        T[kl][el] = f2bf(s[(size_t)(k0 + kl) * srcCols + e0 + el]);
    }
    __syncthreads();
    int rowBase = layer * dstRowPer + e0;
    int colBase = layer * dstColPer + k0;
#pragma unroll
    for (int p = 0; p < 16; ++p) {
        int l = p * 256 + t;
        int eo = l >> 6, ko = l & 63;
        dst[(size_t)(rowBase + eo) * dstStride + colBase + ko] = T[ko][eo];
    }
}

// ====== 256xBN reg-staged pipelined GEMM: C = A[M,K] @ BT[N,K]^T + bias =====
// BK=32, 2-deep LDS double buffer, reg-staging (global->VGPR->swizzled ds_write),
// prefetch distance 2 tiles, counted vmcnt/lgkmcnt (never drain in-loop),
// coalesced LDS-restaged epilogue (bf16 or f32 out).
// Requires: K%64==0, K/32>=2, M%256==0, N%BN==0, grid%8==0.
template <int BN, bool BF16OUT>
__global__ __launch_bounds__(512, 2) void k_gemm_rs(
    const u16* __restrict__ A, const u16* __restrict__ B, void* __restrict__ C,
    const float* __restrict__ bias0, const float* __restrict__ bias1,
    const float* __restrict__ bias2, int K, int lda, int ldb, int ldc,
    int gxmask, int gxshift) {
    constexpr int WN = BN / 64;          // waves along N
    constexpr int WM = 8 / WN;           // waves along M
    constexpr int MF = 256 / (WM * 16);  // m-frags per wave
    constexpr int NF = 4;                // n-frags per wave (64/16)
    constexpr int NCA = 2;               // A 16B-chunks per thread per tile
    constexpr int NCB = (BN * 4) / 512;  // B chunks per thread (2 or 1)
    constexpr int NL = NCA + NCB;        // global loads per thread per tile
    constexpr int SBUF = 16384 + BN * 64;

    __shared__ __align__(16) char smem[131072];
    const int tid = threadIdx.x, lane = tid & 63, wave = tid >> 6;
    const int wr = wave / WN, wc = wave % WN;

    // bijective XCD swizzle (grid multiple of 8)
    const int nwg = gridDim.x, bid = blockIdx.x;
    const int cpx = nwg >> 3;
    const int swz = (bid & 7) * cpx + (bid >> 3);
    const int bx = swz & gxmask, by = swz >> gxshift;
    const int row0 = bx << 8;
    const int col0 = by * BN;

    const size_t lda2 = (size_t)lda * 2, ldb2 = (size_t)ldb * 2;
    // chunk c: row = c>>2, cg = c&3 (16B units along K); swizzled LDS offset
    const char* gA[NCA]; int wA[NCA];
    const char* gB[NCB]; int wB[NCB];
#pragma unroll
    for (int i = 0; i < NCA; ++i) {
        int c = tid + i * 512, row = c >> 2, cg = c & 3;
        gA[i] = (const char*)A + (size_t)(row0 + row) * lda2 + cg * 16;
        wA[i] = row * 64 + ((cg * 16) ^ (((row >> 3) & 1) << 5));
    }
#pragma unroll
    for (int i = 0; i < NCB; ++i) {
        int c = tid + i * 512, row = c >> 2, cg = c & 3;
        gB[i] = (const char*)B + (size_t)(col0 + row) * ldb2 + cg * 16;
        wB[i] = 16384 + row * 64 + ((cg * 16) ^ (((row >> 3) & 1) << 5));
    }

    // per-lane swizzled ds_read offset (frag: row=lane&15, kbyte=(lane>>4)*16)
    const int lane_off = (lane & 15) * 64 +
                         (((lane >> 4) << 4) ^ (((lane >> 3) & 1) << 5));

    f32x4 acc[MF][NF] = {};
    const int nt = K >> 5;
    u16x8 uE[NL], uO[NL];

    auto LOADSET = [&](u16x8* u, int ts) {
#pragma unroll
        for (int i = 0; i < NCA; ++i)
            u[i] = *(const u16x8*)(gA[i] + (size_t)ts * 64);
#pragma unroll
        for (int i = 0; i < NCB; ++i)
            u[NCA + i] = *(const u16x8*)(gB[i] + (size_t)ts * 64);
    };
    auto WRITESET = [&](const u16x8* u, char* buf) {
#pragma unroll
        for (int i = 0; i < NCA; ++i) *(u16x8*)(buf + wA[i]) = u[i];
#pragma unroll
        for (int i = 0; i < NCB; ++i) *(u16x8*)(buf + wB[i]) = u[NCA + i];
    };
    auto WAIT_VM_NL = [&] {
        if constexpr (NL == 4) asm volatile("s_waitcnt vmcnt(4)" ::: "memory");
        else                   asm volatile("s_waitcnt vmcnt(3)" ::: "memory");
    };
    auto WAIT_LGKM_NL = [&] {
        if constexpr (NL == 4) asm volatile("s_waitcnt lgkmcnt(4)" ::: "memory");
        else                   asm volatile("s_waitcnt lgkmcnt(3)" ::: "memory");
    };
    auto TBODY = [&](const char* bufR, const u16x8* uW, char* bufW,
                     u16x8* uL, int tload) {
        const char* aRd = bufR + wr * (MF * 1024) + lane_off;
        const char* bRd = bufR + 16384 + wc * (NF * 1024) + lane_off;
        bf16x8 af[MF], bg[NF];
#pragma unroll
        for (int i = 0; i < MF; ++i) af[i] = *(const bf16x8*)(aRd + i * 1024);
#pragma unroll
        for (int i = 0; i < NF; ++i) bg[i] = *(const bf16x8*)(bRd + i * 1024);
        LOADSET(uL, tload);          // tile t+2 -> regs (async)
        WAIT_VM_NL();                // tile t+1's regs landed
        WRITESET(uW, bufW);          // tile t+1 -> other LDS buffer
        WAIT_LGKM_NL();              // frag ds_reads complete (writes pending)
        __builtin_amdgcn_sched_barrier(0);
        __builtin_amdgcn_s_setprio(1);
#pragma unroll
        for (int m = 0; m < MF; ++m)
#pragma unroll
            for (int n = 0; n < NF; ++n)
                acc[m][n] = MFMA16(af[m], bg[n], acc[m][n]);
        __builtin_amdgcn_s_setprio(0);
        asm volatile("s_waitcnt lgkmcnt(0)" ::: "memory");  // writes visible
        pin_barrier();
    };

    // prologue: tiles 0,1 -> regs; write tile0 to buf0
    LOADSET(uE, 0);
    LOADSET(uO, 1);
    WAIT_VM_NL();
    WRITESET(uE, smem);
    asm volatile("s_waitcnt lgkmcnt(0)" ::: "memory");
    pin_barrier();

    char* buf0 = smem;
    char* buf1 = smem + SBUF;
    for (int t = 0; t < nt; t += 2) {
        int l2 = (t + 2 < nt) ? t + 2 : nt - 1;
        int l3 = (t + 3 < nt) ? t + 3 : nt - 1;
        TBODY(buf0, uO, buf1, uE, l2);   // read tile t,   write t+1, load t+2
        TBODY(buf1, uE, buf0, uO, l3);   // read tile t+1, write t+2, load t+3
    }

    // ---- epilogue: LDS-restage -> full-line coalesced stores ----
    {
        char* cst = smem;
        const int g4 = (lane >> 4) << 2, cl = lane & 15;
#pragma unroll
        for (int n = 0; n < NF; ++n) {
            int col = wc * (NF * 16) + n * 16 + cl;
            float bs = bias0[col0 + col];
            if (bias1) bs += bias1[col0 + col];
            if (bias2) bs += bias2[col0 + col];
#pragma unroll
            for (int m = 0; m < MF; ++m) {
#pragma unroll
                for (int r = 0; r < 4; ++r) {
                    int row = wr * (MF * 16) + m * 16 + g4 + r;
                    float v = acc[m][n][r] + bs;
                    if (BF16OUT) {
                        int scol = col ^ (((row >> 2) & 3) << 3);
                        *(u16*)(cst + row * 512 + scol * 2) = f2bf(v);
                    } else {
                        int scol = col ^ (((row >> 2) & 3) << 2);
                        *(float*)(cst + row * 512 + scol * 4) = v;
                    }
                }
            }
        }
        asm volatile("s_waitcnt lgkmcnt(0)" ::: "memory");
        pin_barrier();
        const int esz = BF16OUT ? 2 : 4;
#pragma unroll
        for (int it = 0; it < 16; ++it) {
            int id = it * 512 + tid;       // 16B chunk: row*32 + c16
            int row = id >> 5, c16 = id & 31;
            int sc16 = c16 ^ ((row >> 2) & 3);
            u16x8 v = *(const u16x8*)(cst + row * 512 + sc16 * 16);
            char* dst = (char*)C + ((size_t)(row0 + row) * ldc + col0) * esz + c16 * 16;
            *(u16x8*)dst = v;
        }
    }
}

// ---------------- attention: one block per (b, segment, head) ---------------
template <int S>
__global__ __launch_bounds__(256) void k_attn(const u16* __restrict__ qkv,
                                              u16* __restrict__ ab, int layer) {
    constexpr int NCT = S / 16;
    constexpr int RPW = (S == 32) ? 1 : S / 64;
    constexpr int ACTIVE = (S == 32) ? 2 : 4;
    constexpr int KST = S / 32;
    constexpr int VSTRIDE = 2 * S;
    constexpr int VMASK = VSTRIDE / 16 - 1;

    __shared__ __align__(16) char KS[S * 128];
    __shared__ __align__(16) char VTS[64 * VSTRIDE];
    __shared__ __align__(16) char PS[S * VSTRIDE];

    const int per_b = (4096 / S) * 16;
    const int b = blockIdx.x / per_b;
    const int r0 = blockIdx.x % per_b;
    const int n = r0 >> 4, h = r0 & 15;
    const int token0 = b * 4096 + n * S;
    const int colQ = layer * 3072 + h * 64;
    const int tid = threadIdx.x, lane = tid & 63, wave = tid >> 6;

    constexpr int CHUNKS = S / 32;
#pragma unroll
    for (int c = 0; c < CHUNKS; ++c) {
        int lc = c * 256 + tid;
        int row = lc >> 3, off = (lc & 7) * 16;
        const char* base = (const char*)qkv + ((size_t)(token0 + row) * 9216 + colQ) * 2 + off;
        u16x8 kv = *(const u16x8*)(base + 1024 * 2);
        *(u16x8*)(KS + row * 128 + (off ^ ((row & 7) << 4))) = kv;
        u16x8 vv = *(const u16x8*)(base + 2048 * 2);
        int cb = off >> 1;
#pragma unroll
        for (int e = 0; e < 8; ++e) {
            int col = cb + e;
            *(u16*)(VTS + col * VSTRIDE + ((row * 2) ^ ((col & VMASK) << 4))) = vv[e];
        }
    }
    __syncthreads();

    f32x4 sacc[RPW][NCT] = {};
    if (wave < ACTIVE) {
#pragma unroll
        for (int rl = 0; rl < RPW; ++rl) {
            int rt = wave * RPW + rl;
#pragma unroll
            for (int ks2 = 0; ks2 < 2; ++ks2) {
                int qrow = token0 + rt * 16 + (lane & 15);
                int kbyte = ks2 * 64 + ((lane >> 4) << 4);
                bf16x8 aq = *(const bf16x8*)((const char*)qkv +
                              ((size_t)qrow * 9216 + colQ) * 2 + kbyte);
#pragma unroll
                for (int ct = 0; ct < NCT; ++ct) {
                    int krow = ct * 16 + (lane & 15);
                    bf16x8 bk = *(const bf16x8*)(KS + krow * 128 + (kbyte ^ ((krow & 7) << 4)));
                    sacc[rl][ct] = MFMA16(aq, bk, sacc[rl][ct]);
                }
            }
        }
#pragma unroll
        for (int rl = 0; rl < RPW; ++rl) {
            int rt = wave * RPW + rl;
#pragma unroll
            for (int r = 0; r < 4; ++r) {
                float vals[NCT];
                float m = -1e30f;
#pragma unroll
                for (int ct = 0; ct < NCT; ++ct) {
                    vals[ct] = sacc[rl][ct][r] * 0.125f;
                    m = fmaxf(m, vals[ct]);
                }
#pragma unroll
                for (int d = 1; d < 16; d <<= 1) m = fmaxf(m, __shfl_xor(m, d, 64));
                float sum = 0.f;
#pragma unroll
                for (int ct = 0; ct < NCT; ++ct) {
                    float p = exp2f((vals[ct] - m) * 1.44269504f);
                    vals[ct] = p;
                    sum += p;
                }
#pragma unroll
                for (int d = 1; d < 16; d <<= 1) sum += __shfl_xor(sum, d, 64);
                float inv = 1.0f / sum;
                int row = rt * 16 + ((lane >> 4) << 2) + r;
#pragma unroll
                for (int ct = 0; ct < NCT; ++ct) {
                    int col = ct * 16 + (lane & 15);
                    *(u16*)(PS + row * VSTRIDE + ((col * 2) ^ ((row & VMASK) << 4))) =
                        f2bf(vals[ct] * inv);
                }
            }
        }
    }
    __syncthreads();

    if (wave < ACTIVE) {
        const int colA = layer * 1024 + h * 64;
#pragma unroll
        for (int rl = 0; rl < RPW; ++rl) {
            int rt = wave * RPW + rl;
            f32x4 oacc[4] = {};
#pragma unroll
            for (int ks2 = 0; ks2 < KST; ++ks2) {
                int kbyte = ks2 * 64 + ((lane >> 4) << 4);
                int prow = rt * 16 + (lane & 15);
                bf16x8 ap = *(const bf16x8*)(PS + prow * VSTRIDE + (kbyte ^ ((prow & VMASK) << 4)));
#pragma unroll
                for (int ct = 0; ct < 4; ++ct) {
                    int vcol = ct * 16 + (lane & 15);
                    bf16x8 bv = *(const bf16x8*)(VTS + vcol * VSTRIDE + (kbyte ^ ((vcol & VMASK) << 4)));
                    oacc[ct] = MFMA16(ap, bv, oacc[ct]);
                }
            }
#pragma unroll
            for (int ct = 0; ct < 4; ++ct) {
#pragma unroll
                for (int r = 0; r < 4; ++r) {
                    int row = token0 + rt * 16 + ((lane >> 4) << 2) + r;
                    int col = colA + ct * 16 + (lane & 15);
                    ab[(size_t)row * 3072 + col] = f2bf(oacc[ct][r]);
                }
            }
        }
    }
}

// ---------------------------------------------------------------------------
extern "C" void kernel_launch(void* const* d_in, const int* in_sizes, int n_in,
                              void* d_out, int out_size, void* d_ws, size_t ws_size,
                              hipStream_t stream) {
    const float* x    = (const float*)d_in[0];
    const float* Wqkv = (const float*)d_in[1];
    const float* bqkv = (const float*)d_in[2];
    const float* Wo   = (const float*)d_in[3];
    const float* bo   = (const float*)d_in[4];

    char* ws = (char*)d_ws;
    u16* XE    = (u16*)(ws);                       // [8192][1024]
    u16* WQKVT = (u16*)(ws + 16777216);            // [9216][1024]
    u16* WOT   = (u16*)(ws + 35651584);            // [1024][3072]
    u16* QKVB  = (u16*)(ws + 41943040);            // [8192][9216]
    u16* ABUF  = (u16*)(ws + 192937984);           // [8192][3072]

    k_prep_xe<<<8192, 256, 0, stream>>>(x, XE);
    k_transpose_cast<<<dim3(16, 48, 3), 256, 0, stream>>>(
        Wqkv, WQKVT, 3072, (size_t)1024 * 3072, 1024, 3072, 0);
    k_transpose_cast<<<dim3(16, 16, 3), 256, 0, stream>>>(
        Wo, WOT, 1024, (size_t)1024 * 1024, 3072, 0, 1024);

    // QKV projection for all 3 layers: [8192,1024] @ [1024,9216]
    // grid = 32 x 36 = 1152 blocks (bx fastest: mask 31, shift 5)
    k_gemm_rs<256, true><<<dim3(1152), 512, 0, stream>>>(
        XE, WQKVT, QKVB, bqkv, nullptr, nullptr, 1024, 1024, 1024, 9216, 31, 5);

    // dilated segment attention per layer
    k_attn<32><<<4096, 256, 0, stream>>>(QKVB, ABUF, 0);
    k_attn<64><<<2048, 256, 0, stream>>>(QKVB, ABUF, 1);
    k_attn<128><<<1024, 256, 0, stream>>>(QKVB, ABUF, 2);

    // fused output projection + layer sum: [8192,3072] @ [3072,1024]
    // grid = 32 x 8 = 256 blocks
    k_gemm_rs<128, false><<<dim3(256), 512, 0, stream>>>(
        ABUF, WOT, d_out, bo, bo + 1024, bo + 2048, 3072, 3072, 3072, 1024, 31, 5);
}